// Round 1
// baseline (229.221 us; speedup 1.0000x reference)
//
#include <hip/hip_runtime.h>
#include <stdint.h>

namespace {
constexpr int kH  = 16;
constexpr int kS  = 8192;
constexpr int kD  = 64;
constexpr int kW  = 1024;
constexpr int kQB = 64;   // queries per block (4 waves x 16 rows)
constexpr int kKT = 32;   // key tile

typedef __attribute__((ext_vector_type(4))) float f32x4;
typedef __attribute__((ext_vector_type(8))) short bf16x8;
typedef __attribute__((ext_vector_type(4))) float float4_t;
typedef __attribute__((ext_vector_type(4))) short short4_t;

__device__ __forceinline__ unsigned short f2bf(float f) {
    union { float fv; uint32_t u; } c; c.fv = f;
    return (unsigned short)((c.u + 0x7fffu + ((c.u >> 16) & 1u)) >> 16);
}

__global__ __launch_bounds__(256)
void swa_fwd(const float* __restrict__ Qg, const float* __restrict__ Kg,
             const float* __restrict__ Vg, float* __restrict__ Og) {
    // K tile: [32 keys][64 d] bf16, row stride 128B, XOR-swizzled
    __shared__ __align__(16) char kt_lds[kKT * kD * 2];
    // V^T tile: [64 d][32 keys] bf16, row stride 64B, XOR-swizzled
    __shared__ __align__(16) char vt_lds[kD * kKT * 2];
    // per-wave P tile: [16 q][32 k] bf16, row stride 64B, XOR-swizzled
    __shared__ __align__(16) char p_lds[4][16 * kKT * 2];

    const int qb   = blockIdx.x;
    const int h    = blockIdx.y;
    const int tid  = threadIdx.x;
    const int w    = tid >> 6;
    const int lane = tid & 63;
    const int lcol = lane & 15;
    const int lgrp = lane >> 4;

    const int q0  = qb * kQB;
    const int qr0 = q0 + w * 16;           // this wave's first query row
    const size_t hb = (size_t)h * kS * kD;

    // ---- Q A-fragments (2 K-chunks of 32), pre-scaled by 1/sqrt(D)=0.125 ----
    // A layout (16x16x32): lane holds A[row = lane&15][k = (lane>>4)*8 + i]
    bf16x8 qfrag[2];
    {
        const float* qp = Qg + hb + (size_t)(qr0 + lcol) * kD + lgrp * 8;
        #pragma unroll
        for (int c = 0; c < 2; ++c) {
            float4_t a = *(const float4_t*)(qp + c * 32);
            float4_t b = *(const float4_t*)(qp + c * 32 + 4);
            bf16x8 f;
            #pragma unroll
            for (int j = 0; j < 4; ++j) {
                f[j]     = (short)f2bf(a[j] * 0.125f);
                f[j + 4] = (short)f2bf(b[j] * 0.125f);
            }
            qfrag[c] = f;
        }
    }

    f32x4 acc[4] = {f32x4{0,0,0,0}, f32x4{0,0,0,0}, f32x4{0,0,0,0}, f32x4{0,0,0,0}};
    float m_r[4] = {-1e30f, -1e30f, -1e30f, -1e30f};
    float l_r[4] = {0.f, 0.f, 0.f, 0.f};

    const int kstart = (q0 - kW > 0) ? (q0 - kW) : 0;
    const int kend   = q0 + kQB;          // exclusive
    const int qimin  = qr0, qimax = qr0 + 15;

    for (int kb = kstart; kb < kend; kb += kKT) {
        __syncthreads();   // previous tile's LDS reads complete
        // ---- stage K (row-major) and V^T (transposed) as bf16, swizzled ----
        #pragma unroll
        for (int it = 0; it < 2; ++it) {
            const int n   = tid + it * 256;     // 512 float4 chunks per tile
            const int key = n >> 4;             // 0..31
            const int d0  = (n & 15) * 4;       // 0..60
            const float4_t kv = *(const float4_t*)(Kg + hb + (size_t)(kb + key) * kD + d0);
            const float4_t vv = *(const float4_t*)(Vg + hb + (size_t)(kb + key) * kD + d0);
            short4_t k4;
            #pragma unroll
            for (int j = 0; j < 4; ++j) k4[j] = (short)f2bf(kv[j]);
            const int kbyt = (key * 128 + d0 * 2) ^ ((key & 7) << 4);
            *(short4_t*)(kt_lds + kbyt) = k4;
            #pragma unroll
            for (int j = 0; j < 4; ++j) {
                const int d    = d0 + j;
                const int vbyt = (d * 64 + key * 2) ^ ((d & 7) << 4);
                *(unsigned short*)(vt_lds + vbyt) = f2bf(vv[j]);
            }
        }
        __syncthreads();   // staging visible

        // wave-level skip of fully-masked tiles (all threads already hit barriers)
        if (kb > qimax || kb + kKT - 1 < qimin - kW) continue;

        // ---- S = Q K^T : two 16x16 key-subtiles, D=64 split into 2 K=32 chunks ----
        f32x4 sc[2] = {f32x4{0,0,0,0}, f32x4{0,0,0,0}};
        #pragma unroll
        for (int st = 0; st < 2; ++st) {
            const int key = st * 16 + lcol;     // B: lane holds K[key=lane&15][k-chunk]
            #pragma unroll
            for (int c = 0; c < 2; ++c) {
                const int byt = (key * 128 + c * 64 + lgrp * 16) ^ ((key & 7) << 4);
                bf16x8 kf = *(const bf16x8*)(kt_lds + byt);
                sc[st] = __builtin_amdgcn_mfma_f32_16x16x32_bf16(qfrag[c], kf, sc[st], 0, 0, 0);
            }
        }

        // ---- online softmax; C layout: row=(lane>>4)*4+r, col=lane&15 ----
        #pragma unroll
        for (int r = 0; r < 4; ++r) {
            const int qi = qr0 + lgrp * 4 + r;
            const int k0 = kb + lcol, k1 = kb + 16 + lcol;
            const bool v0 = (k0 <= qi) && (k0 + kW >= qi);
            const bool v1 = (k1 <= qi) && (k1 + kW >= qi);
            float s0 = v0 ? sc[0][r] : -1e30f;
            float s1 = v1 ? sc[1][r] : -1e30f;
            float t = fmaxf(s0, s1);
            t = fmaxf(t, __shfl_xor(t, 1));
            t = fmaxf(t, __shfl_xor(t, 2));
            t = fmaxf(t, __shfl_xor(t, 4));
            t = fmaxf(t, __shfl_xor(t, 8));
            const float nm    = fmaxf(m_r[r], t);
            const float alpha = __expf(m_r[r] - nm);
            m_r[r] = nm;
            const float p0 = v0 ? __expf(s0 - nm) : 0.f;
            const float p1 = v1 ? __expf(s1 - nm) : 0.f;
            float ps = p0 + p1;
            ps += __shfl_xor(ps, 1);
            ps += __shfl_xor(ps, 2);
            ps += __shfl_xor(ps, 4);
            ps += __shfl_xor(ps, 8);
            l_r[r] = l_r[r] * alpha + ps;
            #pragma unroll
            for (int dt = 0; dt < 4; ++dt) acc[dt][r] *= alpha;
            // stash P (bf16) to wave-private LDS in swizzled [16][32] layout
            const int row = lgrp * 4 + r;
            const int swz = (row & 7) << 4;
            *(unsigned short*)(p_lds[w] + ((row * 64 + lcol * 2)      ^ swz)) = f2bf(p0);
            *(unsigned short*)(p_lds[w] + ((row * 64 + 32 + lcol * 2) ^ swz)) = f2bf(p1);
        }

        // ---- O += P V : A = P[16x32] from LDS, B = V^T tiles ----
        {
            const int prow = lcol;
            bf16x8 pa = *(const bf16x8*)(p_lds[w] + ((prow * 64 + lgrp * 16) ^ ((prow & 7) << 4)));
            #pragma unroll
            for (int dt = 0; dt < 4; ++dt) {
                const int d = dt * 16 + lcol;
                bf16x8 vf = *(const bf16x8*)(vt_lds + ((d * 64 + lgrp * 16) ^ ((d & 7) << 4)));
                acc[dt] = __builtin_amdgcn_mfma_f32_16x16x32_bf16(pa, vf, acc[dt], 0, 0, 0);
            }
        }
    }

    // ---- epilogue: O / l ----
    #pragma unroll
    for (int dt = 0; dt < 4; ++dt) {
        #pragma unroll
        for (int r = 0; r < 4; ++r) {
            const int row = lgrp * 4 + r;
            Og[hb + (size_t)(qr0 + row) * kD + dt * 16 + lcol] = acc[dt][r] / l_r[r];
        }
    }
}
} // namespace

extern "C" void kernel_launch(void* const* d_in, const int* in_sizes, int n_in,
                              void* d_out, int out_size, void* d_ws, size_t ws_size,
                              hipStream_t stream) {
    (void)in_sizes; (void)n_in; (void)out_size; (void)d_ws; (void)ws_size;
    const float* Q = (const float*)d_in[0];
    const float* K = (const float*)d_in[1];
    const float* V = (const float*)d_in[2];
    float* O = (float*)d_out;
    dim3 grid(kS / kQB, kH);
    swa_fwd<<<grid, dim3(256), 0, stream>>>(Q, K, V, O);
}

// Round 3
// 201.791 us; speedup vs baseline: 1.1359x; 1.1359x over previous
//
#include <hip/hip_runtime.h>
#include <stdint.h>

namespace {
constexpr int kH = 16;
constexpr int kS = 8192;
constexpr int kD = 64;
constexpr int kW = 1024;

typedef __attribute__((ext_vector_type(4)))  float float4_t;
typedef __attribute__((ext_vector_type(16))) float f32x16;
typedef __attribute__((ext_vector_type(8)))  short bf16x8;
typedef __attribute__((ext_vector_type(8)))  short short8_t;

__device__ __forceinline__ unsigned short f2bf(float f) {
    union { float fv; uint32_t u; } c; c.fv = f;
    return (unsigned short)((c.u + 0x7fffu + ((c.u >> 16) & 1u)) >> 16);
}

// ---- prepass 1: K fp32 -> bf16 row-major ----
__global__ __launch_bounds__(256)
void prep_k(const float* __restrict__ K, unsigned short* __restrict__ Kb) {
    const int i = (blockIdx.x * 256 + threadIdx.x) * 8;
    float4_t a = *(const float4_t*)(K + i);
    float4_t b = *(const float4_t*)(K + i + 4);
    short8_t o;
    #pragma unroll
    for (int j = 0; j < 4; ++j) { o[j] = (short)f2bf(a[j]); o[j + 4] = (short)f2bf(b[j]); }
    *(short8_t*)(Kb + i) = o;
}

// ---- prepass 2: V fp32 [S][D] -> bf16 V^T [D][S] per head ----
__global__ __launch_bounds__(256)
void prep_v(const float* __restrict__ V, unsigned short* __restrict__ Vt) {
    __shared__ float tile[64][65];
    const int h = blockIdx.y;
    const int s0 = blockIdx.x * 64;
    const int tid = threadIdx.x;
    const size_t hb = (size_t)h * kS * kD;
    #pragma unroll
    for (int it = 0; it < 4; ++it) {
        const int n = tid + it * 256;           // 0..1023
        const int s = n >> 4, d0 = (n & 15) * 4;
        float4_t v = *(const float4_t*)(V + hb + (size_t)(s0 + s) * kD + d0);
        tile[s][d0 + 0] = v[0]; tile[s][d0 + 1] = v[1];
        tile[s][d0 + 2] = v[2]; tile[s][d0 + 3] = v[3];
    }
    __syncthreads();
    #pragma unroll
    for (int it = 0; it < 2; ++it) {
        const int n = tid + it * 256;           // 0..511
        const int d = n >> 3, sc = (n & 7) * 8;
        short8_t o;
        #pragma unroll
        for (int j = 0; j < 8; ++j) o[j] = (short)f2bf(tile[sc + j][d]);
        *(short8_t*)(Vt + (size_t)h * kD * kS + (size_t)d * kS + s0 + sc) = o;
    }
}

// ---- main: no-LDS, no-barrier, swapped-QK^T 32x32 flash loop ----
__global__ __launch_bounds__(256)
void swa_main(const float* __restrict__ Qg, const unsigned short* __restrict__ Kb,
              const unsigned short* __restrict__ Vt, float* __restrict__ Og) {
    // XCD-chunked bijective swizzle: 1024 blocks, each XCD gets 2 whole heads
    const int lid = blockIdx.x + blockIdx.y * gridDim.x;     // 0..1023
    const int swz = (lid & 7) * 128 + (lid >> 3);
    const int h    = swz >> 6;
    const int qblk = swz & 63;

    const int tid  = threadIdx.x;
    const int wv   = tid >> 6;
    const int lane = tid & 63;
    const int lq   = lane & 31;     // this lane's query column / A-row
    const int hi   = lane >> 5;

    const int q0w = qblk * 128 + wv * 32;   // wave's first query
    const int q   = q0w + lq;
    const size_t hb  = (size_t)h * kS * kD;
    const size_t hbv = (size_t)h * kD * kS;

    // Q B-fragments (4 k-chunks of 16), scale = 1/sqrt(D) * log2(e)  (exp2 domain)
    constexpr float qscale = 0.125f * 1.44269504f;
    bf16x8 qf[4];
    {
        const float* qp = Qg + hb + (size_t)q * kD + hi * 8;
        #pragma unroll
        for (int c = 0; c < 4; ++c) {
            float4_t a = *(const float4_t*)(qp + c * 16);
            float4_t b = *(const float4_t*)(qp + c * 16 + 4);
            bf16x8 f;
            #pragma unroll
            for (int j = 0; j < 4; ++j) {
                f[j]     = (short)f2bf(a[j] * qscale);
                f[j + 4] = (short)f2bf(b[j] * qscale);
            }
            qf[c] = f;
        }
    }

    f32x16 acc0, acc1;            // O^T[d][q], d in [0,32) and [32,64)
    #pragma unroll
    for (int r = 0; r < 16; ++r) { acc0[r] = 0.f; acc1[r] = 0.f; }
    float m = -1e30f, l = 0.f;

    const int wstart = (q0w >= kW) ? (q0w - kW) : 0;
    for (int kb = wstart; kb <= q0w; kb += 32) {
        // ---- S^T = K · Q^T  (C: row = key-rel, col = q) ----
        f32x16 st;
        #pragma unroll
        for (int r = 0; r < 16; ++r) st[r] = 0.f;
        const unsigned short* kp = Kb + hb + (size_t)(kb + lq) * kD + hi * 8;
        #pragma unroll
        for (int c = 0; c < 4; ++c) {
            bf16x8 kf = *(const bf16x8*)(kp + c * 16);
            st = __builtin_amdgcn_mfma_f32_32x32x16_bf16(kf, qf[c], st, 0, 0, 0);
        }

        // ---- mask (wave-uniform interior fast path) ----
        float p[16];
        const bool interior = (kb + 31 <= q0w) && (kb >= q0w + 31 - kW);
        if (interior) {
            #pragma unroll
            for (int r = 0; r < 16; ++r) p[r] = st[r];
        } else {
            #pragma unroll
            for (int r = 0; r < 16; ++r) {
                const int ki = kb + (r & 3) + 8 * (r >> 2) + 4 * hi;
                const bool ok = (ki <= q) && (ki + kW >= q);
                p[r] = ok ? st[r] : -1e30f;
            }
        }

        // ---- online softmax (exp2 domain), defer-max THR=8 ----
        float tm = p[0];
        #pragma unroll
        for (int r = 1; r < 16; ++r) tm = fmaxf(tm, p[r]);
        tm = fmaxf(tm, __shfl_xor(tm, 32));
        if (!__all(tm <= m + 8.f)) {
            const float nm = fmaxf(m, tm);
            const float al = exp2f(m - nm);
            l *= al;
            #pragma unroll
            for (int r = 0; r < 16; ++r) { acc0[r] *= al; acc1[r] *= al; }
            m = nm;
        }
        float ps = 0.f;
        #pragma unroll
        for (int r = 0; r < 16; ++r) { p[r] = exp2f(p[r] - m); ps += p[r]; }
        ps += __shfl_xor(ps, 32);
        l += ps;

        // ---- P^T -> bf16 B-fragments: 8 cvt_pk + 4 permlane32_swap ----
        // wrd[j] (pre-swap): lanes<32 keys (2j,2j+1) of {0..3,8..11,16..19,24..27};
        //                    lanes>=32 same +4.  Swap dst keeps lo, gets src.lo in hi.
        unsigned int wrd[8];
        #pragma unroll
        for (int j = 0; j < 8; ++j)
            asm("v_cvt_pk_bf16_f32 %0, %1, %2" : "=v"(wrd[j]) : "v"(p[2 * j]), "v"(p[2 * j + 1]));
        asm("v_permlane32_swap_b32 %0, %1" : "+v"(wrd[0]), "+v"(wrd[2]));
        asm("v_permlane32_swap_b32 %0, %1" : "+v"(wrd[1]), "+v"(wrd[3]));
        asm("v_permlane32_swap_b32 %0, %1" : "+v"(wrd[4]), "+v"(wrd[6]));
        asm("v_permlane32_swap_b32 %0, %1" : "+v"(wrd[5]), "+v"(wrd[7]));
        union U { unsigned int u[4]; bf16x8 v; };
        U u0, u1;
        u0.u[0] = wrd[0]; u0.u[1] = wrd[1]; u0.u[2] = wrd[2]; u0.u[3] = wrd[3];
        u1.u[0] = wrd[4]; u1.u[1] = wrd[5]; u1.u[2] = wrd[6]; u1.u[3] = wrd[7];
        bf16x8 pb[2] = {u0.v, u1.v};

        // ---- O^T += V^T · P^T ----
        const unsigned short* vp = Vt + hbv + (size_t)lq * kS + kb + hi * 8;
        #pragma unroll
        for (int c = 0; c < 2; ++c) {
            bf16x8 v0 = *(const bf16x8*)(vp + c * 16);
            bf16x8 v1 = *(const bf16x8*)(vp + 32 * kS + c * 16);
            acc0 = __builtin_amdgcn_mfma_f32_32x32x16_bf16(v0, pb[c], acc0, 0, 0, 0);
            acc1 = __builtin_amdgcn_mfma_f32_32x32x16_bf16(v1, pb[c], acc1, 0, 0, 0);
        }
    }

    // ---- epilogue: O[q][d] = acc^T / l ----
    const float rl = 1.f / l;
    float* op = Og + hb + (size_t)q * kD;
    #pragma unroll
    for (int g = 0; g < 4; ++g) {
        float4_t o0, o1;
        #pragma unroll
        for (int j = 0; j < 4; ++j) { o0[j] = acc0[g * 4 + j] * rl; o1[j] = acc1[g * 4 + j] * rl; }
        *(float4_t*)(op + g * 8 + hi * 4)      = o0;
        *(float4_t*)(op + 32 + g * 8 + hi * 4) = o1;
    }
}
} // namespace

extern "C" void kernel_launch(void* const* d_in, const int* in_sizes, int n_in,
                              void* d_out, int out_size, void* d_ws, size_t ws_size,
                              hipStream_t stream) {
    (void)in_sizes; (void)n_in; (void)out_size; (void)ws_size;
    const float* Q = (const float*)d_in[0];
    const float* K = (const float*)d_in[1];
    const float* V = (const float*)d_in[2];
    float* O = (float*)d_out;
    unsigned short* Kb = (unsigned short*)d_ws;
    unsigned short* Vt = Kb + (size_t)kH * kS * kD;

    prep_k<<<dim3(kH * kS * kD / 2048), dim3(256), 0, stream>>>(K, Kb);
    prep_v<<<dim3(kS / 64, kH), dim3(256), 0, stream>>>(V, Vt);
    swa_main<<<dim3(64, kH), dim3(256), 0, stream>>>(Q, Kb, Vt, O);
}

// Round 4
// 115.790 us; speedup vs baseline: 1.9796x; 1.7427x over previous
//
#include <hip/hip_runtime.h>
#include <stdint.h>

namespace {
constexpr int kH = 16;
constexpr int kS = 8192;
constexpr int kD = 64;
constexpr int kW = 1024;

typedef __attribute__((ext_vector_type(4)))  float float4_t;
typedef __attribute__((ext_vector_type(16))) float f32x16;
typedef __attribute__((ext_vector_type(8)))  short bf16x8;
typedef __attribute__((ext_vector_type(8)))  short short8_t;

__device__ __forceinline__ unsigned short f2bf(float f) {
    union { float fv; uint32_t u; } c; c.fv = f;
    return (unsigned short)((c.u + 0x7fffu + ((c.u >> 16) & 1u)) >> 16);
}

__device__ __forceinline__ float fexp2(float x) {
#if __has_builtin(__builtin_amdgcn_exp2f)
    return __builtin_amdgcn_exp2f(x);
#else
    return exp2f(x);
#endif
}

// ---- prepass 1: K fp32 -> bf16 row-major ----
__global__ __launch_bounds__(256)
void prep_k(const float* __restrict__ K, unsigned short* __restrict__ Kb) {
    const int i = (blockIdx.x * 256 + threadIdx.x) * 8;
    float4_t a = *(const float4_t*)(K + i);
    float4_t b = *(const float4_t*)(K + i + 4);
    short8_t o;
    #pragma unroll
    for (int j = 0; j < 4; ++j) { o[j] = (short)f2bf(a[j]); o[j + 4] = (short)f2bf(b[j]); }
    *(short8_t*)(Kb + i) = o;
}

// ---- prepass 2: V fp32 [S][D] -> bf16 V^T [D][S] per head ----
__global__ __launch_bounds__(256)
void prep_v(const float* __restrict__ V, unsigned short* __restrict__ Vt) {
    __shared__ float tile[64][65];
    const int h = blockIdx.y;
    const int s0 = blockIdx.x * 64;
    const int tid = threadIdx.x;
    const size_t hb = (size_t)h * kS * kD;
    #pragma unroll
    for (int it = 0; it < 4; ++it) {
        const int n = tid + it * 256;
        const int s = n >> 4, d0 = (n & 15) * 4;
        float4_t v = *(const float4_t*)(V + hb + (size_t)(s0 + s) * kD + d0);
        tile[s][d0 + 0] = v[0]; tile[s][d0 + 1] = v[1];
        tile[s][d0 + 2] = v[2]; tile[s][d0 + 3] = v[3];
    }
    __syncthreads();
    #pragma unroll
    for (int it = 0; it < 2; ++it) {
        const int n = tid + it * 256;
        const int d = n >> 3, sc = (n & 7) * 8;
        short8_t o;
        #pragma unroll
        for (int j = 0; j < 8; ++j) o[j] = (short)f2bf(tile[sc + j][d]);
        *(short8_t*)(Vt + (size_t)h * kD * kS + (size_t)d * kS + s0 + sc) = o;
    }
}

// ---- main: 64q/wave, register-double-buffered K/V, swapped-QK^T 32x32 ----
__global__ __launch_bounds__(128)
void swa_main(const float* __restrict__ Qg, const unsigned short* __restrict__ Kb,
              const unsigned short* __restrict__ Vt, float* __restrict__ Og) {
    const int lid  = blockIdx.x;                       // 0..1023
    const int swz  = (lid & 7) * 128 + (lid >> 3);     // XCD-chunked, bijective
    const int h    = swz >> 6;
    const int qblk = swz & 63;

    const int tid  = threadIdx.x;
    const int wv   = tid >> 6;
    const int lane = tid & 63;
    const int lq   = lane & 31;
    const int hi   = lane >> 5;

    const int q0w = qblk * 128 + wv * 64;              // wave's first query
    const size_t hb  = (size_t)h * kS * kD;
    const size_t hbv = (size_t)h * kD * kS;

    // Q B-fragments for both 32-query subtiles; scale folded with log2(e)
    constexpr float qscale = 0.125f * 1.44269504f;
    bf16x8 qf[2][4];
    #pragma unroll
    for (int s = 0; s < 2; ++s) {
        const float* qp = Qg + hb + (size_t)(q0w + 32 * s + lq) * kD + hi * 8;
        #pragma unroll
        for (int c = 0; c < 4; ++c) {
            float4_t a = *(const float4_t*)(qp + c * 16);
            float4_t b = *(const float4_t*)(qp + c * 16 + 4);
            bf16x8 f;
            #pragma unroll
            for (int j = 0; j < 4; ++j) {
                f[j]     = (short)f2bf(a[j] * qscale);
                f[j + 4] = (short)f2bf(b[j] * qscale);
            }
            qf[s][c] = f;
        }
    }

    f32x16 acc[2][2];   // [subtile][d-half]: O^T fragments
    #pragma unroll
    for (int s = 0; s < 2; ++s)
        #pragma unroll
        for (int hf = 0; hf < 2; ++hf)
            #pragma unroll
            for (int r = 0; r < 16; ++r) acc[s][hf][r] = 0.f;
    float m[2] = {-1e30f, -1e30f};
    float l[2] = {0.f, 0.f};

    const int kend   = q0w + 64;
    const int wstart = (q0w >= kW) ? (q0w - kW) : 0;

    const unsigned short* kbase = Kb + hb  + (size_t)lq * kD + hi * 8;
    const unsigned short* vbase = Vt + hbv + (size_t)lq * kS + hi * 8;

    // prologue: load tile 0
    bf16x8 kc[4], vc[4];
    {
        const unsigned short* kp = kbase + (size_t)wstart * kD;
        const unsigned short* vp = vbase + wstart;
        #pragma unroll
        for (int c = 0; c < 4; ++c) kc[c] = *(const bf16x8*)(kp + c * 16);
        #pragma unroll
        for (int c = 0; c < 2; ++c) {
            vc[c]     = *(const bf16x8*)(vp + c * 16);
            vc[c + 2] = *(const bf16x8*)(vp + (size_t)32 * kS + c * 16);
        }
    }

    for (int kb = wstart; kb < kend; kb += 32) {
        // ---- S^T = K · Q^T for both subtiles (2 independent chains) ----
        f32x16 st0, st1;
        #pragma unroll
        for (int r = 0; r < 16; ++r) { st0[r] = 0.f; st1[r] = 0.f; }
        #pragma unroll
        for (int c = 0; c < 4; ++c) {
            st0 = __builtin_amdgcn_mfma_f32_32x32x16_bf16(kc[c], qf[0][c], st0, 0, 0, 0);
            st1 = __builtin_amdgcn_mfma_f32_32x32x16_bf16(kc[c], qf[1][c], st1, 0, 0, 0);
        }

        // ---- prefetch next-tile K (kc dead after QK) ----
        const int kbn = (kb + 32 < kend) ? kb + 32 : kb;
        bf16x8 kn[4];
        {
            const unsigned short* kp = kbase + (size_t)kbn * kD;
            #pragma unroll
            for (int c = 0; c < 4; ++c) kn[c] = *(const bf16x8*)(kp + c * 16);
        }

        // ---- per-subtile softmax + PV ----
        #pragma unroll
        for (int s = 0; s < 2; ++s) {
            const int qs = q0w + 32 * s;
            if (kb > qs || kb < qs - kW) continue;       // inactive edge tile
            const f32x16& st = (s == 0) ? st0 : st1;

            float p[16];
            const bool interior = (kb <= qs - 32) && (kb >= qs - 992);
            if (interior) {
                #pragma unroll
                for (int r = 0; r < 16; ++r) p[r] = st[r];
            } else {
                #pragma unroll
                for (int r = 0; r < 16; ++r) {
                    const int ki = kb + (r & 3) + 8 * (r >> 2) + 4 * hi;
                    const int q  = qs + lq;
                    const bool ok = (ki <= q) && (ki + kW >= q);
                    p[r] = ok ? st[r] : -1e30f;
                }
            }

            float tm = p[0];
            #pragma unroll
            for (int r = 1; r < 16; ++r) tm = fmaxf(tm, p[r]);
            tm = fmaxf(tm, __shfl_xor(tm, 32));
            if (!__all(tm <= m[s] + 8.f)) {
                const float nm = fmaxf(m[s], tm);
                const float al = fexp2(m[s] - nm);
                l[s] *= al;
                #pragma unroll
                for (int r = 0; r < 16; ++r) { acc[s][0][r] *= al; acc[s][1][r] *= al; }
                m[s] = nm;
            }
            float ps = 0.f;
            #pragma unroll
            for (int r = 0; r < 16; ++r) { p[r] = fexp2(p[r] - m[s]); ps += p[r]; }
            ps += __shfl_xor(ps, 32);
            l[s] += ps;

            // P^T -> bf16 B-frags: 8 cvt_pk + 4 permlane32_swap (R3-verified order)
            unsigned int wrd[8];
            #pragma unroll
            for (int j = 0; j < 8; ++j)
                asm("v_cvt_pk_bf16_f32 %0, %1, %2" : "=v"(wrd[j]) : "v"(p[2 * j]), "v"(p[2 * j + 1]));
            asm("v_permlane32_swap_b32 %0, %1" : "+v"(wrd[0]), "+v"(wrd[2]));
            asm("v_permlane32_swap_b32 %0, %1" : "+v"(wrd[1]), "+v"(wrd[3]));
            asm("v_permlane32_swap_b32 %0, %1" : "+v"(wrd[4]), "+v"(wrd[6]));
            asm("v_permlane32_swap_b32 %0, %1" : "+v"(wrd[5]), "+v"(wrd[7]));
            union U { unsigned int u[4]; bf16x8 v; };
            U u0, u1;
            u0.u[0] = wrd[0]; u0.u[1] = wrd[1]; u0.u[2] = wrd[2]; u0.u[3] = wrd[3];
            u1.u[0] = wrd[4]; u1.u[1] = wrd[5]; u1.u[2] = wrd[6]; u1.u[3] = wrd[7];

            acc[s][0] = __builtin_amdgcn_mfma_f32_32x32x16_bf16(vc[0], u0.v, acc[s][0], 0, 0, 0);
            acc[s][1] = __builtin_amdgcn_mfma_f32_32x32x16_bf16(vc[2], u0.v, acc[s][1], 0, 0, 0);
            acc[s][0] = __builtin_amdgcn_mfma_f32_32x32x16_bf16(vc[1], u1.v, acc[s][0], 0, 0, 0);
            acc[s][1] = __builtin_amdgcn_mfma_f32_32x32x16_bf16(vc[3], u1.v, acc[s][1], 0, 0, 0);
        }

        // ---- prefetch next-tile V (vc dead after PV) ----
        bf16x8 vn[4];
        {
            const unsigned short* vp = vbase + kbn;
            #pragma unroll
            for (int c = 0; c < 2; ++c) {
                vn[c]     = *(const bf16x8*)(vp + c * 16);
                vn[c + 2] = *(const bf16x8*)(vp + (size_t)32 * kS + c * 16);
            }
        }
        #pragma unroll
        for (int c = 0; c < 4; ++c) { kc[c] = kn[c]; vc[c] = vn[c]; }
    }

    // ---- epilogue ----
    #pragma unroll
    for (int s = 0; s < 2; ++s) {
        const float rl = 1.f / l[s];
        float* op = Og + hb + (size_t)(q0w + 32 * s + lq) * kD;
        #pragma unroll
        for (int g = 0; g < 4; ++g) {
            float4_t o0, o1;
            #pragma unroll
            for (int j = 0; j < 4; ++j) {
                o0[j] = acc[s][0][g * 4 + j] * rl;
                o1[j] = acc[s][1][g * 4 + j] * rl;
            }
            *(float4_t*)(op + g * 8 + hi * 4)      = o0;
            *(float4_t*)(op + 32 + g * 8 + hi * 4) = o1;
        }
    }
}
} // namespace

extern "C" void kernel_launch(void* const* d_in, const int* in_sizes, int n_in,
                              void* d_out, int out_size, void* d_ws, size_t ws_size,
                              hipStream_t stream) {
    (void)in_sizes; (void)n_in; (void)out_size; (void)ws_size;
    const float* Q = (const float*)d_in[0];
    const float* K = (const float*)d_in[1];
    const float* V = (const float*)d_in[2];
    float* O = (float*)d_out;
    unsigned short* Kb = (unsigned short*)d_ws;
    unsigned short* Vt = Kb + (size_t)kH * kS * kD;

    prep_k<<<dim3(kH * kS * kD / 2048), dim3(256), 0, stream>>>(K, Kb);
    prep_v<<<dim3(kS / 64, kH), dim3(256), 0, stream>>>(V, Vt);
    swa_main<<<dim3(1024), dim3(128), 0, stream>>>(Q, Kb, Vt, O);
}

// Round 5
// 88.255 us; speedup vs baseline: 2.5972x; 1.3120x over previous
//
#include <hip/hip_runtime.h>
#include <stdint.h>

namespace {
constexpr int kH = 16;
constexpr int kS = 8192;
constexpr int kD = 64;
constexpr int kW = 1024;

typedef __attribute__((ext_vector_type(4)))  float float4_t;
typedef __attribute__((ext_vector_type(16))) float f32x16;
typedef __attribute__((ext_vector_type(8)))  short bf16x8;
typedef __attribute__((ext_vector_type(8)))  short short8_t;

__device__ __forceinline__ unsigned short f2bf(float f) {
    union { float fv; uint32_t u; } c; c.fv = f;
    return (unsigned short)((c.u + 0x7fffu + ((c.u >> 16) & 1u)) >> 16);
}

__device__ __forceinline__ float fexp2(float x) {
#if __has_builtin(__builtin_amdgcn_exp2f)
    return __builtin_amdgcn_exp2f(x);
#else
    return exp2f(x);
#endif
}

__device__ __forceinline__ void gload16(const void* g, char* l) {
    __builtin_amdgcn_global_load_lds(
        (const __attribute__((address_space(1))) void*)g,
        (__attribute__((address_space(3))) void*)l, 16, 0, 0);
}

// ---- prepass 1: K fp32 -> bf16 row-major ----
__global__ __launch_bounds__(256)
void prep_k(const float* __restrict__ K, unsigned short* __restrict__ Kb) {
    const int i = (blockIdx.x * 256 + threadIdx.x) * 8;
    float4_t a = *(const float4_t*)(K + i);
    float4_t b = *(const float4_t*)(K + i + 4);
    short8_t o;
    #pragma unroll
    for (int j = 0; j < 4; ++j) { o[j] = (short)f2bf(a[j]); o[j + 4] = (short)f2bf(b[j]); }
    *(short8_t*)(Kb + i) = o;
}

// ---- prepass 2: V fp32 [S][D] -> bf16 V^T [D][S] per head ----
__global__ __launch_bounds__(256)
void prep_v(const float* __restrict__ V, unsigned short* __restrict__ Vt) {
    __shared__ float tile[64][65];
    const int h = blockIdx.y;
    const int s0 = blockIdx.x * 64;
    const int tid = threadIdx.x;
    const size_t hb = (size_t)h * kS * kD;
    #pragma unroll
    for (int it = 0; it < 4; ++it) {
        const int n = tid + it * 256;
        const int s = n >> 4, d0 = (n & 15) * 4;
        float4_t v = *(const float4_t*)(V + hb + (size_t)(s0 + s) * kD + d0);
        tile[s][d0 + 0] = v[0]; tile[s][d0 + 1] = v[1];
        tile[s][d0 + 2] = v[2]; tile[s][d0 + 3] = v[3];
    }
    __syncthreads();
    #pragma unroll
    for (int it = 0; it < 2; ++it) {
        const int n = tid + it * 256;
        const int d = n >> 3, sc = (n & 7) * 8;
        short8_t o;
        #pragma unroll
        for (int j = 0; j < 8; ++j) o[j] = (short)f2bf(tile[sc + j][d]);
        *(short8_t*)(Vt + (size_t)h * kD * kS + (size_t)d * kS + s0 + sc) = o;
    }
}

// ---- main: LDS-staged KT=64 double-buffer, counted vmcnt, raw barriers ----
__global__ __launch_bounds__(256, 2)
void swa_main(const float* __restrict__ Qg, const unsigned short* __restrict__ Kb,
              const unsigned short* __restrict__ Vt, float* __restrict__ Og) {
    // per buffer: [0,8K) = K tile [64 keys][128B], [8K,16K) = V^T tile [64 d][128B]
    __shared__ __align__(16) char lds[2][16384];

    const int lid  = blockIdx.x;                    // 0..511
    const int swz  = (lid & 7) * 64 + (lid >> 3);   // XCD-chunked, bijective
    const int h    = swz >> 5;
    const int qblk = swz & 31;

    const int tid  = threadIdx.x;
    const int wv   = tid >> 6;
    const int lane = tid & 63;
    const int lq   = lane & 31;
    const int hi   = lane >> 5;

    const int q0b = qblk * 256;          // block's first query
    const int q0w = q0b + wv * 64;       // wave's first query
    const size_t hb  = (size_t)h * kS * kD;
    const size_t hbv = (size_t)h * kD * kS;

    // ---- Q B-fragments for both 32-q subtiles; scale folded with log2(e) ----
    constexpr float qscale = 0.125f * 1.44269504f;
    bf16x8 qf[2][4];
    #pragma unroll
    for (int s = 0; s < 2; ++s) {
        const float* qp = Qg + hb + (size_t)(q0w + 32 * s + lq) * kD + hi * 8;
        #pragma unroll
        for (int c = 0; c < 4; ++c) {
            float4_t a = *(const float4_t*)(qp + c * 16);
            float4_t b = *(const float4_t*)(qp + c * 16 + 4);
            bf16x8 f;
            #pragma unroll
            for (int j = 0; j < 4; ++j) {
                f[j]     = (short)f2bf(a[j] * qscale);
                f[j + 4] = (short)f2bf(b[j] * qscale);
            }
            qf[s][c] = f;
        }
    }

    f32x16 acc[2][2];
    #pragma unroll
    for (int s = 0; s < 2; ++s)
        #pragma unroll
        for (int hf = 0; hf < 2; ++hf)
            #pragma unroll
            for (int r = 0; r < 16; ++r) acc[s][hf][r] = 0.f;
    float m[2] = {-1e30f, -1e30f};
    float l[2] = {0.f, 0.f};

    const int kstart = (q0b >= kW) ? q0b - kW : 0;
    const int nt     = (q0b + 256 - kstart) >> 6;   // 64-key tiles

    // staging: dest chunk n = tid + i*256 (linear); src chunk c = n ^ ((n>>3)&7)
    // (involution matching read-side byte swizzle e ^ ((row&7)<<4), row=e>>7)
    int srcK[2], srcV[2];
    #pragma unroll
    for (int i = 0; i < 2; ++i) {
        const int n = tid + i * 256;
        const int c = n ^ ((n >> 3) & 7);
        srcK[i] = (c >> 3) * 64 + (c & 7) * 8;           // element off in K tile
        srcV[i] = (c >> 3) * kS + (c & 7) * 8;           // element off in V^T (+kb)
    }
    const unsigned short* KbH = Kb + hb;
    const unsigned short* VtH = Vt + hbv;

    auto stage = [&](int buf, int kb) {
        const unsigned short* Kt = KbH + (size_t)kb * 64;
        const unsigned short* Vq = VtH + kb;
        #pragma unroll
        for (int i = 0; i < 2; ++i) {
            const int db = i * 4096 + wv * 1024;        // wave-uniform dest base
            gload16(Kt + srcK[i], &lds[buf][db]);
            gload16(Vq + srcV[i], &lds[buf][8192 + db]);
        }
    };

    stage(0, kstart);
    for (int t = 0; t < nt; ++t) {
        const int kb  = kstart + t * 64;
        const int kbn = (t + 1 < nt) ? kb + 64 : kb;
        stage((t + 1) & 1, kbn);                        // prefetch next tile
        asm volatile("s_waitcnt vmcnt(4)" ::: "memory"); // current tile's 4 loads done
        __builtin_amdgcn_s_barrier();
        asm volatile("" ::: "memory");

        const char* Kl = lds[t & 1];
        const char* Vl = lds[t & 1] + 8192;

        #pragma unroll
        for (int half = 0; half < 2; ++half) {
            const int kh = kb + half * 32;
            if (kh > q0w + 63 || kh < q0w - kW) continue;   // inactive for wave

            // K A-frags: row = key, 4-way-min conflict via XOR swizzle
            const int krow = half * 32 + lq;
            const int ksw  = (krow & 7) << 4;
            bf16x8 kf[4];
            #pragma unroll
            for (int c = 0; c < 4; ++c)
                kf[c] = *(const bf16x8*)(Kl + ((krow * 128 + c * 32 + hi * 16) ^ ksw));

            f32x16 st0, st1;
            #pragma unroll
            for (int r = 0; r < 16; ++r) { st0[r] = 0.f; st1[r] = 0.f; }
            __builtin_amdgcn_s_setprio(1);
            #pragma unroll
            for (int c = 0; c < 4; ++c) {
                st0 = __builtin_amdgcn_mfma_f32_32x32x16_bf16(kf[c], qf[0][c], st0, 0, 0, 0);
                st1 = __builtin_amdgcn_mfma_f32_32x32x16_bf16(kf[c], qf[1][c], st1, 0, 0, 0);
            }
            __builtin_amdgcn_s_setprio(0);

            // V A-frags (issue before softmax; latency hides under it)
            const int vsw = (lq & 7) << 4;
            bf16x8 vf[4];
            #pragma unroll
            for (int dh = 0; dh < 2; ++dh)
                #pragma unroll
                for (int kc = 0; kc < 2; ++kc)
                    vf[dh * 2 + kc] = *(const bf16x8*)(
                        Vl + (((dh * 32 + lq) * 128 + half * 64 + kc * 32 + hi * 16) ^ vsw));

            #pragma unroll
            for (int s = 0; s < 2; ++s) {
                const int qs = q0w + 32 * s;
                if (kh > qs || kh < qs - kW) continue;    // 32-aligned => exact
                const f32x16& st = (s == 0) ? st0 : st1;

                float p[16];
                const bool interior = (kh <= qs - 32) && (kh >= qs - 992);
                if (interior) {
                    #pragma unroll
                    for (int r = 0; r < 16; ++r) p[r] = st[r];
                } else {
                    #pragma unroll
                    for (int r = 0; r < 16; ++r) {
                        const int ki = kh + (r & 3) + 8 * (r >> 2) + 4 * hi;
                        const int q  = qs + lq;
                        const bool ok = (ki <= q) && (ki + kW >= q);
                        p[r] = ok ? st[r] : -1e30f;
                    }
                }

                float tm = p[0];
                #pragma unroll
                for (int r = 1; r < 16; ++r) tm = fmaxf(tm, p[r]);
                tm = fmaxf(tm, __shfl_xor(tm, 32));
                if (!__all(tm <= m[s] + 8.f)) {
                    const float nm = fmaxf(m[s], tm);
                    const float al = fexp2(m[s] - nm);
                    l[s] *= al;
                    #pragma unroll
                    for (int r = 0; r < 16; ++r) { acc[s][0][r] *= al; acc[s][1][r] *= al; }
                    m[s] = nm;
                }
                float ps = 0.f;
                #pragma unroll
                for (int r = 0; r < 16; ++r) { p[r] = fexp2(p[r] - m[s]); ps += p[r]; }
                ps += __shfl_xor(ps, 32);
                l[s] += ps;

                // P^T -> bf16 B-frags (R3-verified cvt_pk + permlane order)
                unsigned int wrd[8];
                #pragma unroll
                for (int j = 0; j < 8; ++j)
                    asm("v_cvt_pk_bf16_f32 %0, %1, %2" : "=v"(wrd[j]) : "v"(p[2 * j]), "v"(p[2 * j + 1]));
                asm("v_permlane32_swap_b32 %0, %1" : "+v"(wrd[0]), "+v"(wrd[2]));
                asm("v_permlane32_swap_b32 %0, %1" : "+v"(wrd[1]), "+v"(wrd[3]));
                asm("v_permlane32_swap_b32 %0, %1" : "+v"(wrd[4]), "+v"(wrd[6]));
                asm("v_permlane32_swap_b32 %0, %1" : "+v"(wrd[5]), "+v"(wrd[7]));
                union U { unsigned int u[4]; bf16x8 v; };
                U u0, u1;
                u0.u[0] = wrd[0]; u0.u[1] = wrd[1]; u0.u[2] = wrd[2]; u0.u[3] = wrd[3];
                u1.u[0] = wrd[4]; u1.u[1] = wrd[5]; u1.u[2] = wrd[6]; u1.u[3] = wrd[7];

                __builtin_amdgcn_s_setprio(1);
                acc[s][0] = __builtin_amdgcn_mfma_f32_32x32x16_bf16(vf[0], u0.v, acc[s][0], 0, 0, 0);
                acc[s][1] = __builtin_amdgcn_mfma_f32_32x32x16_bf16(vf[2], u0.v, acc[s][1], 0, 0, 0);
                acc[s][0] = __builtin_amdgcn_mfma_f32_32x32x16_bf16(vf[1], u1.v, acc[s][0], 0, 0, 0);
                acc[s][1] = __builtin_amdgcn_mfma_f32_32x32x16_bf16(vf[3], u1.v, acc[s][1], 0, 0, 0);
                __builtin_amdgcn_s_setprio(0);
            }
        }

        asm volatile("" ::: "memory");
        __builtin_amdgcn_s_barrier();                   // all done reading buf before rewrite
        asm volatile("" ::: "memory");
    }

    // ---- epilogue ----
    #pragma unroll
    for (int s = 0; s < 2; ++s) {
        const float rl = 1.f / l[s];
        float* op = Og + hb + (size_t)(q0w + 32 * s + lq) * kD;
        #pragma unroll
        for (int g = 0; g < 4; ++g) {
            float4_t o0, o1;
            #pragma unroll
            for (int j = 0; j < 4; ++j) {
                o0[j] = acc[s][0][g * 4 + j] * rl;
                o1[j] = acc[s][1][g * 4 + j] * rl;
            }
            *(float4_t*)(op + g * 8 + hi * 4)      = o0;
            *(float4_t*)(op + 32 + g * 8 + hi * 4) = o1;
        }
    }
}
} // namespace

extern "C" void kernel_launch(void* const* d_in, const int* in_sizes, int n_in,
                              void* d_out, int out_size, void* d_ws, size_t ws_size,
                              hipStream_t stream) {
    (void)in_sizes; (void)n_in; (void)out_size; (void)ws_size;
    const float* Q = (const float*)d_in[0];
    const float* K = (const float*)d_in[1];
    const float* V = (const float*)d_in[2];
    float* O = (float*)d_out;
    unsigned short* Kb = (unsigned short*)d_ws;
    unsigned short* Vt = Kb + (size_t)kH * kS * kD;

    prep_k<<<dim3(kH * kS * kD / 2048), dim3(256), 0, stream>>>(K, Kb);
    prep_v<<<dim3(kS / 64, kH), dim3(256), 0, stream>>>(V, Vt);
    swa_main<<<dim3(512), dim3(256), 0, stream>>>(Q, Kb, Vt, O);
}

// Round 6
// 71.862 us; speedup vs baseline: 3.1898x; 1.2281x over previous
//
#include <hip/hip_runtime.h>
#include <stdint.h>

namespace {
constexpr int kH = 16;
constexpr int kS = 8192;
constexpr int kD = 64;
constexpr int kW = 1024;

typedef __attribute__((ext_vector_type(4)))  float float4_t;
typedef __attribute__((ext_vector_type(16))) float f32x16;
typedef __attribute__((ext_vector_type(8)))  short bf16x8;
typedef __attribute__((ext_vector_type(8)))  short short8_t;

__device__ __forceinline__ unsigned short f2bf(float f) {
    union { float fv; uint32_t u; } c; c.fv = f;
    return (unsigned short)((c.u + 0x7fffu + ((c.u >> 16) & 1u)) >> 16);
}

__device__ __forceinline__ float fexp2(float x) {
#if __has_builtin(__builtin_amdgcn_exp2f)
    return __builtin_amdgcn_exp2f(x);
#else
    return exp2f(x);
#endif
}

__device__ __forceinline__ void gload16(const void* g, char* l) {
    __builtin_amdgcn_global_load_lds(
        (const __attribute__((address_space(1))) void*)g,
        (__attribute__((address_space(3))) void*)l, 16, 0, 0);
}

// ---- prepass 1: K fp32 -> bf16 row-major ----
__global__ __launch_bounds__(256)
void prep_k(const float* __restrict__ K, unsigned short* __restrict__ Kb) {
    const int i = (blockIdx.x * 256 + threadIdx.x) * 8;
    float4_t a = *(const float4_t*)(K + i);
    float4_t b = *(const float4_t*)(K + i + 4);
    short8_t o;
    #pragma unroll
    for (int j = 0; j < 4; ++j) { o[j] = (short)f2bf(a[j]); o[j + 4] = (short)f2bf(b[j]); }
    *(short8_t*)(Kb + i) = o;
}

// ---- prepass 2: V fp32 [S][D] -> bf16 V^T [D][S] per head ----
__global__ __launch_bounds__(256)
void prep_v(const float* __restrict__ V, unsigned short* __restrict__ Vt) {
    __shared__ float tile[64][65];
    const int h = blockIdx.y;
    const int s0 = blockIdx.x * 64;
    const int tid = threadIdx.x;
    const size_t hb = (size_t)h * kS * kD;
    #pragma unroll
    for (int it = 0; it < 4; ++it) {
        const int n = tid + it * 256;
        const int s = n >> 4, d0 = (n & 15) * 4;
        float4_t v = *(const float4_t*)(V + hb + (size_t)(s0 + s) * kD + d0);
        tile[s][d0 + 0] = v[0]; tile[s][d0 + 1] = v[1];
        tile[s][d0 + 2] = v[2]; tile[s][d0 + 3] = v[3];
    }
    __syncthreads();
    #pragma unroll
    for (int it = 0; it < 2; ++it) {
        const int n = tid + it * 256;
        const int d = n >> 3, sc = (n & 7) * 8;
        short8_t o;
        #pragma unroll
        for (int j = 0; j < 8; ++j) o[j] = (short)f2bf(tile[sc + j][d]);
        *(short8_t*)(Vt + (size_t)h * kD * kS + (size_t)d * kS + s0 + sc) = o;
    }
}

// ---- main: 32 q/wave, 128 q/block, LDS KT=64 dbuf, max-free softmax ----
__global__ __launch_bounds__(256, 4)
void swa_main(const float* __restrict__ Qg, const unsigned short* __restrict__ Kb,
              const unsigned short* __restrict__ Vt, float* __restrict__ Og) {
    // per buffer: [0,8K) K tile [64 keys][128B], [8K,16K) V^T tile [64 d][128B]
    __shared__ __align__(16) char lds[2][16384];

    const int lid  = blockIdx.x;                      // 0..1023
    const int swz  = (lid & 7) * 128 + (lid >> 3);    // XCD-chunked, bijective
    const int h    = swz >> 6;
    const int qblk = swz & 63;

    const int tid  = threadIdx.x;
    const int wv   = tid >> 6;
    const int lane = tid & 63;
    const int lq   = lane & 31;
    const int hi   = lane >> 5;

    const int q0b = qblk * 128;          // block's first query
    const int qs  = q0b + wv * 32;       // wave's subtile start
    const int q   = qs + lq;             // this lane's query
    const size_t hb  = (size_t)h * kS * kD;
    const size_t hbv = (size_t)h * kD * kS;

    // ---- Q B-fragment; scale folded with log2(e) ----
    constexpr float qscale = 0.125f * 1.44269504f;
    bf16x8 qf[4];
    {
        const float* qp = Qg + hb + (size_t)q * kD + hi * 8;
        #pragma unroll
        for (int c = 0; c < 4; ++c) {
            float4_t a = *(const float4_t*)(qp + c * 16);
            float4_t b = *(const float4_t*)(qp + c * 16 + 4);
            bf16x8 f;
            #pragma unroll
            for (int j = 0; j < 4; ++j) {
                f[j]     = (short)f2bf(a[j] * qscale);
                f[j + 4] = (short)f2bf(b[j] * qscale);
            }
            qf[c] = f;
        }
    }

    f32x16 acc[2];                        // O^T fragments, d-halves
    #pragma unroll
    for (int hf = 0; hf < 2; ++hf)
        #pragma unroll
        for (int r = 0; r < 16; ++r) acc[hf][r] = 0.f;
    float l4[4] = {0.f, 0.f, 0.f, 0.f};   // per-lane partial denominators

    const int kstart = (q0b >= kW) ? q0b - kW : 0;
    const int nt     = (q0b + 128 - kstart) >> 6;     // 64-key tiles

    // staging: dest chunk n = tid + i*256 (linear); src chunk c = n ^ ((n>>3)&7)
    int srcK[2], srcV[2];
    #pragma unroll
    for (int i = 0; i < 2; ++i) {
        const int n = tid + i * 256;
        const int c = n ^ ((n >> 3) & 7);
        srcK[i] = (c >> 3) * 64 + (c & 7) * 8;
        srcV[i] = (c >> 3) * kS + (c & 7) * 8;
    }
    const unsigned short* KbH = Kb + hb;
    const unsigned short* VtH = Vt + hbv;

    auto stage = [&](int buf, int kb) {
        const unsigned short* Kt = KbH + (size_t)kb * 64;
        const unsigned short* Vq = VtH + kb;
        #pragma unroll
        for (int i = 0; i < 2; ++i) {
            const int db = i * 4096 + wv * 1024;
            gload16(Kt + srcK[i], &lds[buf][db]);
            gload16(Vq + srcV[i], &lds[buf][8192 + db]);
        }
    };

    stage(0, kstart);
    for (int t = 0; t < nt; ++t) {
        const int kb  = kstart + t * 64;
        const int kbn = (t + 1 < nt) ? kb + 64 : kb;
        stage((t + 1) & 1, kbn);                         // prefetch next tile
        asm volatile("s_waitcnt vmcnt(4)" ::: "memory"); // current tile staged
        __builtin_amdgcn_s_barrier();
        asm volatile("" ::: "memory");

        const char* Kl = lds[t & 1];
        const char* Vl = lds[t & 1] + 8192;

        #pragma unroll
        for (int half = 0; half < 2; ++half) {
            const int kh = kb + half * 32;
            if (kh <= qs && kh >= qs - kW) {             // wave-uniform active check
                // K A-frags
                const int krow = half * 32 + lq;
                const int ksw  = (krow & 7) << 4;
                bf16x8 kf[4];
                #pragma unroll
                for (int c = 0; c < 4; ++c)
                    kf[c] = *(const bf16x8*)(Kl + ((krow * 128 + c * 32 + hi * 16) ^ ksw));

                f32x16 st;
                #pragma unroll
                for (int r = 0; r < 16; ++r) st[r] = 0.f;
                __builtin_amdgcn_s_setprio(1);
                #pragma unroll
                for (int c = 0; c < 4; ++c)
                    st = __builtin_amdgcn_mfma_f32_32x32x16_bf16(kf[c], qf[c], st, 0, 0, 0);
                __builtin_amdgcn_s_setprio(0);

                // V A-frags (issue early; latency hides under softmax)
                const int vsw = (lq & 7) << 4;
                bf16x8 vf[4];
                #pragma unroll
                for (int dh = 0; dh < 2; ++dh)
                    #pragma unroll
                    for (int kc = 0; kc < 2; ++kc)
                        vf[dh * 2 + kc] = *(const bf16x8*)(
                            Vl + (((dh * 32 + lq) * 128 + half * 64 + kc * 32 + hi * 16) ^ vsw));

                // ---- max-free softmax numerators (exp2 domain) ----
                float p[16];
                const bool interior = (kh <= qs - 32) && (kh >= qs - 992);
                if (interior) {
                    #pragma unroll
                    for (int r = 0; r < 16; ++r) p[r] = fexp2(st[r]);
                } else {
                    #pragma unroll
                    for (int r = 0; r < 16; ++r) {
                        const int ki = kh + (r & 3) + 8 * (r >> 2) + 4 * hi;
                        const bool ok = (ki <= q) && (ki + kW >= q);
                        const float e = fexp2(st[r]);
                        p[r] = ok ? e : 0.f;
                    }
                }
                #pragma unroll
                for (int r = 0; r < 16; ++r) l4[r & 3] += p[r];

                // P^T -> bf16 B-frags (verified cvt_pk + permlane order)
                unsigned int wrd[8];
                #pragma unroll
                for (int j = 0; j < 8; ++j)
                    asm("v_cvt_pk_bf16_f32 %0, %1, %2" : "=v"(wrd[j]) : "v"(p[2 * j]), "v"(p[2 * j + 1]));
                asm("v_permlane32_swap_b32 %0, %1" : "+v"(wrd[0]), "+v"(wrd[2]));
                asm("v_permlane32_swap_b32 %0, %1" : "+v"(wrd[1]), "+v"(wrd[3]));
                asm("v_permlane32_swap_b32 %0, %1" : "+v"(wrd[4]), "+v"(wrd[6]));
                asm("v_permlane32_swap_b32 %0, %1" : "+v"(wrd[5]), "+v"(wrd[7]));
                union U { unsigned int u[4]; bf16x8 v; };
                U u0, u1;
                u0.u[0] = wrd[0]; u0.u[1] = wrd[1]; u0.u[2] = wrd[2]; u0.u[3] = wrd[3];
                u1.u[0] = wrd[4]; u1.u[1] = wrd[5]; u1.u[2] = wrd[6]; u1.u[3] = wrd[7];

                __builtin_amdgcn_s_setprio(1);
                acc[0] = __builtin_amdgcn_mfma_f32_32x32x16_bf16(vf[0], u0.v, acc[0], 0, 0, 0);
                acc[1] = __builtin_amdgcn_mfma_f32_32x32x16_bf16(vf[2], u0.v, acc[1], 0, 0, 0);
                acc[0] = __builtin_amdgcn_mfma_f32_32x32x16_bf16(vf[1], u1.v, acc[0], 0, 0, 0);
                acc[1] = __builtin_amdgcn_mfma_f32_32x32x16_bf16(vf[3], u1.v, acc[1], 0, 0, 0);
                __builtin_amdgcn_s_setprio(0);
            }
        }

        asm volatile("" ::: "memory");
        __builtin_amdgcn_s_barrier();                   // buf fully read before rewrite
        asm volatile("" ::: "memory");
    }

    // ---- epilogue: combine denominators, normalize, store ----
    float l = (l4[0] + l4[1]) + (l4[2] + l4[3]);
    l += __shfl_xor(l, 32);
    const float rl = 1.f / l;
    float* op = Og + hb + (size_t)q * kD;
    #pragma unroll
    for (int g = 0; g < 4; ++g) {
        float4_t o0, o1;
        #pragma unroll
        for (int j = 0; j < 4; ++j) {
            o0[j] = acc[0][g * 4 + j] * rl;
            o1[j] = acc[1][g * 4 + j] * rl;
        }
        *(float4_t*)(op + g * 8 + hi * 4)      = o0;
        *(float4_t*)(op + 32 + g * 8 + hi * 4) = o1;
    }
}
} // namespace

extern "C" void kernel_launch(void* const* d_in, const int* in_sizes, int n_in,
                              void* d_out, int out_size, void* d_ws, size_t ws_size,
                              hipStream_t stream) {
    (void)in_sizes; (void)n_in; (void)out_size; (void)ws_size;
    const float* Q = (const float*)d_in[0];
    const float* K = (const float*)d_in[1];
    const float* V = (const float*)d_in[2];
    float* O = (float*)d_out;
    unsigned short* Kb = (unsigned short*)d_ws;
    unsigned short* Vt = Kb + (size_t)kH * kS * kD;

    prep_k<<<dim3(kH * kS * kD / 2048), dim3(256), 0, stream>>>(K, Kb);
    prep_v<<<dim3(kS / 64, kH), dim3(256), 0, stream>>>(V, Vt);
    swa_main<<<dim3(1024), dim3(256), 0, stream>>>(Q, Kb, Vt, O);
}